// Round 13
// baseline (571.465 us; speedup 1.0000x reference)
//
#include <hip/hip_runtime.h>
#include <cstdio>
#include <cstdint>

#define CCH 64      // channels C
#define EMBD 32     // embedding dim
#define NBD 8       // num radial basis
#define RHD 32      // radial hidden
#define NATTR 100   // distinct node_attr values
#define TBINS 64    // radial table intervals (65 sample points)

static constexpr float MAXR    = 2.5f;
static constexpr float INVNN   = 0.17677669529663687f;  // 1/sqrt(32)
static constexpr float EFK     = 2.5298221281347035f;   // sqrt(2/2.5)*sqrt(8)
static constexpr float SQRT3   = 1.7320508075688772f;
static constexpr float PI_F    = 3.14159265358979323846f;

typedef __fp16 v2h __attribute__((ext_vector_type(2)));

__device__ __forceinline__ float sigm_(float x) { return 1.f / (1.f + __expf(-x)); }
__device__ __forceinline__ float silu_(float x) { return x / (1.f + __expf(-x)); }
// bf16 helpers
__device__ __forceinline__ unsigned f2bfu(float f) {
    unsigned u = __float_as_uint(f);
    return (u + 0x7FFF + ((u >> 16) & 1)) >> 16;
}
__device__ __forceinline__ unsigned pack2(float lo, float hi) {
    return f2bfu(lo) | (f2bfu(hi) << 16);
}
__device__ __forceinline__ float ulo(unsigned u) { return __uint_as_float(u << 16); }
__device__ __forceinline__ float uhi(unsigned u) { return __uint_as_float(u & 0xFFFF0000u); }
// f16 helpers
__device__ __forceinline__ v2h u2h(unsigned u) { v2h h; __builtin_memcpy(&h, &u, 4); return h; }
__device__ __forceinline__ unsigned pkh(float a, float b) {
    v2h h = __builtin_amdgcn_cvt_pkrtz(a, b);
    unsigned u; __builtin_memcpy(&u, &h, 4); return u;
}
__device__ __forceinline__ unsigned short h1(float f) {
    __fp16 h = (__fp16)f; unsigned short s; __builtin_memcpy(&s, &h, 2); return s;
}
__device__ __forceinline__ float dot2(unsigned a, unsigned b, float c) {
    return __builtin_amdgcn_fdot2(u2h(a), u2h(b), c, false);
}
__device__ __forceinline__ float hlo(unsigned u) { v2h h = u2h(u); return (float)h.x; }
__device__ __forceinline__ float hhi(unsigned u) { v2h h = u2h(u); return (float)h.y; }

// ---------------- Q = polar factor of uplift_M (64x2) ----------------
__global__ void kQ(const float* M, float* Q) {
    int c = threadIdx.x;  // 64 threads = 1 wave
    float m0 = M[2*c], m1 = M[2*c+1];
    float a = m0*m0, b = m0*m1, d = m1*m1;
    for (int o = 32; o > 0; o >>= 1) {
        a += __shfl_xor(a, o); b += __shfl_xor(b, o); d += __shfl_xor(d, o);
    }
    float det = a*d - b*b;
    float s = sqrtf(det);
    float t = sqrtf(a + d + 2.f*s);
    float inv = 1.f / (s*t);
    float i00 = (d + s)*inv, i01 = -b*inv, i11 = (a + s)*inv;
    Q[2*c]   = m0*i00 + m1*i01;
    Q[2*c+1] = m0*i01 + m1*i11;
}

// ---------------- radial table (bf16 pair), INVNN folded in ----------------
__global__ void kRadTab(const float* __restrict__ rW1, const float* __restrict__ rb1,
                        const float* __restrict__ rW2, unsigned* __restrict__ tab) {
    int bin = blockIdx.x;
    int l   = blockIdx.y;
    int lane = threadIdx.x;
    float r = bin * (MAXR / TBINS);
    float safe = fmaxf(r, 1e-9f);
    float invSafe = 1.f / safe;
    float th = PI_F * r * (1.f / MAXR);
    float s0, c0;
    __sincosf(th, &s0, &c0);
    __shared__ float hidS[RHD];
    if (lane < RHD) {
        float hs = rb1[l*RHD + lane];
        float sPrev = 0.f, sCur = s0, twoC = 2.f*c0;
        #pragma unroll
        for (int b = 0; b < NBD; ++b) {
            float efb = EFK * sCur * invSafe;
            hs = fmaf(efb, rW1[(l*NBD + b)*RHD + lane], hs);
            float sN = fmaf(twoC, sCur, -sPrev);
            sPrev = sCur; sCur = sN;
        }
        hidS[lane] = silu_(hs);
    }
    __syncthreads();
    float w1 = 0.f, w2 = 0.f;
    #pragma unroll
    for (int rr = 0; rr < RHD; ++rr) {
        float h = hidS[rr];
        w1 = fmaf(h, rW2[(l*RHD + rr)*128 + lane], w1);
        w2 = fmaf(h, rW2[(l*RHD + rr)*128 + 64 + lane], w2);
    }
    float cut = s0*s0;
    float coef = SQRT3 * cut * invSafe * INVNN;
    tab[((size_t)l*(TBINS+1) + bin)*64 + lane] = pack2(w1*coef, w2*coef);
}

// ---------------- pack siV as f16 channel pairs ----------------
__global__ void kPackW(const float* __restrict__ siv, unsigned* __restrict__ siVp) {
    int l = blockIdx.y;
    int i = blockIdx.x*256 + threadIdx.x;   // 0..2047
    int cp = i >> 6, o = i & 63;
    siVp[l*2048 + i] = pkh(siv[l*4096 + (2*cp)*64 + o], siv[l*4096 + (2*cp+1)*64 + o]);
}

// ---------------- init: y0v, pos4, layer-0 lin1 via dot2 (y0s == 0) ----------------
__global__ __launch_bounds__(256) void kInitLin(const float* __restrict__ x, const float* __restrict__ Qg,
        const float* __restrict__ L1v,
        float* __restrict__ yAv, float4* __restrict__ pos4,
        uint2* __restrict__ mv, int n) {
    __shared__ unsigned wPk[32*64];            // h2(L1v[c][o], L1v[c+1][o]) : 8 KB
    __shared__ __align__(16) unsigned bc[4][32][4];
    int t = threadIdx.x;
    for (int i = t; i < 32*64; i += 256) {
        int cp = i >> 6, o = i & 63;
        wPk[i] = pkh(L1v[(2*cp)*64 + o], L1v[(2*cp+1)*64 + o]);
    }
    __syncthreads();
    int lane = t & 63;
    int wid = t >> 6;
    float q0 = Qg[2*lane], q1 = Qg[2*lane+1];
    for (int node = blockIdx.x*4 + wid; node < n; node += gridDim.x*4) {
        const float* xr = x + (size_t)node*6;
        float x0 = xr[0], x1 = xr[1], x2 = xr[2], x3 = xr[3], x4 = xr[4], x5 = xr[5];
        float y0 = q0*x0 + q1*x3;
        float y1 = q0*x1 + q1*x4;
        float y2 = q0*x2 + q1*x5;
        float* yv = yAv + (size_t)node*192 + lane*3;
        yv[0] = y0; yv[1] = y1; yv[2] = y2;
        if (lane == 0) pos4[node] = (float4){x0, x1, x2, 0.f};
        {
            unsigned short* p = (unsigned short*)bc[wid][lane >> 1];
            int sub = lane & 1;
            p[0*2+sub] = h1(y0); p[1*2+sub] = h1(y1); p[2*2+sub] = h1(y2);
        }
        float a0 = 0.f, a1 = 0.f, a2 = 0.f;
        #pragma unroll 8
        for (int cp = 0; cp < 32; ++cp) {
            uint4 b = *(const uint4*)&bc[wid][cp][0];
            unsigned wp = wPk[cp*64 + lane];
            a0 = dot2(b.x, wp, a0);
            a1 = dot2(b.y, wp, a1);
            a2 = dot2(b.z, wp, a2);
        }
        mv[(size_t)node*64 + lane] = (uint2){ pack2(a0, a1), pack2(a2, 0.f) };
    }
}

// ---------------- CSR degree + offsets (two cursor copies for the 2 kGeom passes) ----------------
__global__ void kHist(const int* dst, int* cnt, int e) {
    int i = blockIdx.x*blockDim.x + threadIdx.x;
    if (i < e) atomicAdd(&cnt[dst[i]], 1);
}

__global__ void kScan(const int* cnt, int* offs, int* curG0, int* curG1, int n) {
    __shared__ int part[1024];
    int t = threadIdx.x;
    int chunk = (n + 1023) >> 10;
    int lo = t*chunk, hi = min(lo + chunk, n);
    int s = 0;
    for (int i = lo; i < hi; ++i) s += cnt[i];
    part[t] = s;
    __syncthreads();
    for (int o = 1; o < 1024; o <<= 1) {
        int w = (t >= o) ? part[t - o] : 0;
        __syncthreads();
        part[t] += w;
        __syncthreads();
    }
    int run = part[t] - s;
    for (int i = lo; i < hi; ++i) {
        int cv = cnt[i];
        offs[i] = run; curG0[i] = run; curG1[i] = run;
        run += cv;
    }
    if (t == 1023) offs[n] = part[1023];
}

// ---------------- attr-sort: bucket nodes by attr (for kOutComb L1 locality) ----------------
__global__ void kHistA(const int* __restrict__ attr, int* __restrict__ acnt, int n) {
    int i = blockIdx.x*256 + threadIdx.x;
    if (i < n) atomicAdd(&acnt[attr[i]], 1);
}
__global__ void kScanA(const int* __restrict__ acnt, int* __restrict__ acur) {
    __shared__ int part[128];
    int t = threadIdx.x;
    int v = (t < NATTR) ? acnt[t] : 0;
    part[t] = v;
    __syncthreads();
    for (int o = 1; o < 128; o <<= 1) {
        int w = (t >= o) ? part[t - o] : 0;
        __syncthreads();
        part[t] += w;
        __syncthreads();
    }
    if (t < NATTR) acur[t] = part[t] - v;   // exclusive prefix
}
__global__ void kScatterA(const int* __restrict__ attr, int* __restrict__ acur,
                          int* __restrict__ nodeOrd, int n) {
    int i = blockIdx.x*256 + threadIdx.x;
    if (i < n) {
        int p = atomicAdd(&acur[attr[i]], 1);
        nodeOrd[p] = i;
    }
}

// ---------------- geometry + CSR scatter + cut compaction in one pass ----------------
__global__ __launch_bounds__(256) void kGeom(const float4* __restrict__ pos4,
        const int* __restrict__ esrc, const int* __restrict__ edst,
        int* __restrict__ cur, uint4* __restrict__ rec, int e) {
    int i = blockIdx.x*256 + threadIdx.x;
    if (i >= e) return;
    int s = esrc[i], d = edst[i];
    float4 pa = pos4[s], pb = pos4[d];
    float ex = pa.x - pb.x, ey = pa.y - pb.y, ez = pa.z - pb.z;
    float el2 = ex*ex + ey*ey + ez*ez;
    if (el2 >= MAXR*MAXR) return;          // cut == 0: drop the edge entirely
    float elen = sqrtf(el2);
    float u = fminf(elen * ((float)TBINS / MAXR), 63.98f);
    int p = atomicAdd(&cur[d], 1);
    rec[p] = (uint4){ (unsigned)s, pkh(ex, ey), pkh(ez, u), 0u };
}

// ---------------- T tables: interleaved uint4 {tsa2, tsb2, tv2, pad} ----------------
__global__ __launch_bounds__(256) void kT3(const float* __restrict__ embT,
        const float* __restrict__ scs, const float* __restrict__ scv,
        unsigned* __restrict__ TallU) {
    int cp = blockIdx.x, l = blockIdx.y, ag = blockIdx.z;  // 32 x 2 x 5
    int c0 = 2*cp, c1 = c0 + 1;
    __shared__ float sS0[32*128], sS1[32*128], sV0[32*64], sV1[32*64], sE[20*EMBD];
    int t = threadIdx.x;
    const float* p0 = scs + ((size_t)(l*CCH + c0)*EMBD)*128;
    const float* p1 = scs + ((size_t)(l*CCH + c1)*EMBD)*128;
    for (int i = t; i < 32*128; i += 256) { sS0[i] = p0[i]; sS1[i] = p1[i]; }
    const float* q0 = scv + ((size_t)(l*CCH + c0)*EMBD)*64;
    const float* q1 = scv + ((size_t)(l*CCH + c1)*EMBD)*64;
    for (int i = t; i < 32*64; i += 256) { sV0[i] = q0[i]; sV1[i] = q1[i]; }
    const float* eb = embT + (size_t)ag*20*EMBD;
    for (int i = t; i < 20*EMBD; i += 256) sE[i] = eb[i];
    __syncthreads();
    if (t < 128) {
        int o = t;
        for (int a = 0; a < 20; ++a) {
            float acc0 = 0.f, acc1 = 0.f;
            #pragma unroll
            for (int e = 0; e < EMBD; ++e) {
                float ev = sE[a*EMBD + e];
                acc0 = fmaf(ev, sS0[e*128 + o], acc0);
                acc1 = fmaf(ev, sS1[e*128 + o], acc1);
            }
            int aa = ag*20 + a;
            size_t idx = ((size_t)(l*NATTR + aa)*32 + cp)*64 + (o & 63);
            TallU[idx*4 + (o >> 6)] = pkh(acc0, acc1);
        }
    } else if (t < 192) {
        int o = t - 128;
        for (int a = 0; a < 20; ++a) {
            float acc0 = 0.f, acc1 = 0.f;
            #pragma unroll
            for (int e = 0; e < EMBD; ++e) {
                float ev = sE[a*EMBD + e];
                acc0 = fmaf(ev, sV0[e*64 + o], acc0);
                acc1 = fmaf(ev, sV1[e*64 + o], acc1);
            }
            int aa = ag*20 + a;
            size_t idx = ((size_t)(l*NATTR + aa)*32 + cp)*64 + o;
            TallU[idx*4 + 2] = pkh(acc0, acc1);
        }
    }
}

// ---------------- lin1 (layer 1): dot2 ----------------
__global__ __launch_bounds__(256) void kLin1(const float* __restrict__ ys, const float* __restrict__ yv,
        const float* __restrict__ L1s, const float* __restrict__ L1v,
        uint2* __restrict__ mv, int n) {
    __shared__ uint2 wPk[32*64];               // {h2(L1s c,c+1), h2(L1v c,c+1)} : 16 KB
    __shared__ __align__(16) unsigned bc[4][32][4];
    int t = threadIdx.x;
    for (int i = t; i < 32*64; i += 256) {
        int cp = i >> 6, o = i & 63;
        wPk[i] = (uint2){ pkh(L1s[(2*cp)*64 + o], L1s[(2*cp+1)*64 + o]),
                          pkh(L1v[(2*cp)*64 + o], L1v[(2*cp+1)*64 + o]) };
    }
    __syncthreads();
    int lane = t & 63;
    int wid = t >> 6;
    for (int node = blockIdx.x*4 + wid; node < n; node += gridDim.x*4) {
        float ys_r = ys[(size_t)node*64 + lane];
        const float* yvp = yv + (size_t)node*192 + lane*3;
        float y0 = yvp[0], y1 = yvp[1], y2 = yvp[2];
        {
            unsigned short* p = (unsigned short*)bc[wid][lane >> 1];
            int sub = lane & 1;
            p[0*2+sub] = h1(y0); p[1*2+sub] = h1(y1);
            p[2*2+sub] = h1(y2); p[3*2+sub] = h1(ys_r);
        }
        float as = 0.f, a0 = 0.f, a1 = 0.f, a2 = 0.f;
        #pragma unroll 8
        for (int cp = 0; cp < 32; ++cp) {
            uint4 b = *(const uint4*)&bc[wid][cp][0];
            uint2 wp = wPk[cp*64 + lane];
            as = dot2(b.w, wp.x, as);
            a0 = dot2(b.x, wp.y, a0);
            a1 = dot2(b.y, wp.y, a1);
            a2 = dot2(b.z, wp.y, a2);
        }
        mv[(size_t)node*64 + lane] = (uint2){ pack2(a0, a1), pack2(a2, as) };
    }
}

// ---------------- aggregation: compacted records, 2-deep mv prefetch ----------------
template<int WITHV>
__global__ __launch_bounds__(256) void kAgg(const uint4* __restrict__ rec,
        const uint2* __restrict__ mv,
        const int* __restrict__ offs, const int* __restrict__ endA,
        const unsigned* __restrict__ tabG,
        float* __restrict__ aggS, float* __restrict__ aggV, int n) {
    __shared__ unsigned tab[(TBINS+1)*64];   // 16.6 KB bf16 pairs (coef*INVNN folded)
    __shared__ float red[4][64][4];
    int t = threadIdx.x;
    for (int i = t; i < (TBINS+1)*64; i += 256) tab[i] = tabG[i];
    __syncthreads();
    int lane = t & 63;
    int wid = t >> 6;

    for (int node = blockIdx.x; node < n; node += gridDim.x) {
        int beg = offs[node], end = endA[node];
        float accS = 0.f, av0 = 0.f, av1 = 0.f, av2 = 0.f;
        int idx = beg + wid;
        uint4 r0 = (uint4){0u,0u,0u,0u}, r1 = r0;
        uint2 m0 = (uint2){0u,0u}, m1 = m0;
        if (idx < end)     { r0 = rec[idx];   m0 = mv[(size_t)r0.x*64 + lane]; }
        if (idx + 4 < end) { r1 = rec[idx+4]; m1 = mv[(size_t)r1.x*64 + lane]; }
        for (; idx < end; idx += 4) {
            uint4 r2 = (uint4){0u,0u,0u,0u};
            uint2 m2 = (uint2){0u,0u};
            if (idx + 8 < end) { r2 = rec[idx+8]; m2 = mv[(size_t)r2.x*64 + lane]; }
            float ex = hlo(r0.y), ey = hhi(r0.y);
            float ez = hlo(r0.z), u = hhi(r0.z);
            int i0 = (int)u;
            float fr = u - (float)i0;
            unsigned t0 = tab[i0*64 + lane];
            unsigned t1 = tab[i0*64 + 64 + lane];
            float w1 = fmaf(fr, ulo(t1) - ulo(t0), ulo(t0));
            float w2 = fmaf(fr, uhi(t1) - uhi(t0), uhi(t0));
            float dv = ulo(m0.x)*ex + uhi(m0.x)*ey + ulo(m0.y)*ez;
            accS = fmaf(w2, dv, accS);
            if (WITHV) {
                float tt = w1 * uhi(m0.y);
                av0 = fmaf(tt, ex, av0); av1 = fmaf(tt, ey, av1); av2 = fmaf(tt, ez, av2);
            }
            r0 = r1; m0 = m1; r1 = r2; m1 = m2;
        }
        red[wid][lane][0] = accS; red[wid][lane][1] = av0;
        red[wid][lane][2] = av1;  red[wid][lane][3] = av2;
        __syncthreads();
        if (wid == 0) {
            float rs = red[0][lane][0] + red[1][lane][0] + red[2][lane][0] + red[3][lane][0];
            aggS[(size_t)node*64 + lane] = rs;     // INVNN folded into tab
            float r0s = red[0][lane][1] + red[1][lane][1] + red[2][lane][1] + red[3][lane][1];
            float r1s = red[0][lane][2] + red[1][lane][2] + red[2][lane][2] + red[3][lane][2];
            float r2s = red[0][lane][3] + red[1][lane][3] + red[2][lane][3] + red[3][lane][3];
            float* ap = aggV + (size_t)node*192 + lane*3;
            ap[0] = r0s; ap[1] = r1s; ap[2] = r2s;
        }
        __syncthreads();
    }
}

// ---------------- fused out+gating+combine; attr-sorted chunks for Tall L1 locality ----------------
template<int L0>
__global__ __launch_bounds__(256) void kOutComb(const float* __restrict__ ys, const float* __restrict__ yv,
        const float* __restrict__ yoldv,
        const float* __restrict__ aggS, const float* __restrict__ aggV,
        const int* __restrict__ attr, const int* __restrict__ nodeOrd,
        const float* __restrict__ L2s, const float* __restrict__ L2v,
        const uint4* __restrict__ Tall,
        const float* __restrict__ siS, const unsigned* __restrict__ siVp, const float* __restrict__ Qg,
        const float* __restrict__ hArr, const float* __restrict__ mArr, int li,
        float* __restrict__ newS, float* __restrict__ newV,
        float4* __restrict__ pos4out, float* __restrict__ xout6, int n) {
    __shared__ uint4 wAll[32*64];    // {h2(L2s a), h2(L2s b), h2(L2v), h2(siS)} : 32 KB
    __shared__ __align__(16) unsigned bc[4][32][8];  // 4 KB
    int t = threadIdx.x;
    for (int i = t; i < 32*64; i += 256) {
        int cp = i >> 6, o = i & 63;
        wAll[i] = (uint4){ pkh(L2s[(2*cp)*128 + o],      L2s[(2*cp+1)*128 + o]),
                           pkh(L2s[(2*cp)*128 + 64 + o], L2s[(2*cp+1)*128 + 64 + o]),
                           pkh(L2v[(2*cp)*64 + o], L2v[(2*cp+1)*64 + o]),
                           L0 ? 0u : pkh(siS[(2*cp)*64 + o], siS[(2*cp+1)*64 + o]) };
    }
    __syncthreads();
    int lane = t & 63;
    int wid = t >> 6;
    unsigned svr[32];
    #pragma unroll
    for (int cp = 0; cp < 32; ++cp) svr[cp] = siVp[cp*64 + lane];
    float hh = hArr[li]; hh *= hh;
    float m = mArr[li];
    float q0 = Qg[2*lane], q1 = Qg[2*lane+1];
    // contiguous chunk of the attr-sorted order per wave -> Tall slice stays L1-hot
    int nw = gridDim.x*4;
    int chunk = (n + nw - 1) / nw;
    int start = (blockIdx.x*4 + wid) * chunk;
    int stop = min(start + chunk, n);
    for (int ii = start; ii < stop; ++ii) {
        int node = nodeOrd[ii];
        int a = attr[node];
        const unsigned* tA = (const unsigned*)(Tall + (size_t)a*2048);
        float as_r = aggS[(size_t)node*64 + lane];
        float ys_r = L0 ? 0.f : ys[(size_t)node*64 + lane];
        const float* avp = aggV + (size_t)node*192 + lane*3;
        float av0 = avp[0], av1 = avp[1], av2 = avp[2];
        const float* yvp = yv + (size_t)node*192 + lane*3;
        float by0 = yvp[0], by1 = yvp[1], by2 = yvp[2];
        {
            unsigned short* p = (unsigned short*)bc[wid][lane >> 1];
            int sub = lane & 1;
            p[0*2+sub] = h1(as_r); p[1*2+sub] = L0 ? (unsigned short)0 : h1(ys_r);
            p[2*2+sub] = h1(av0);  p[3*2+sub] = h1(by0);
            p[4*2+sub] = h1(av1);  p[5*2+sub] = h1(by1);
            p[6*2+sub] = h1(av2);  p[7*2+sub] = h1(by2);
        }
        float oS0=0.f, oS1=0.f, ov0=0.f, ov1=0.f, ov2=0.f;
        float q2s=0.f, qv0=0.f, qv1=0.f, qv2=0.f;
        #pragma unroll 4
        for (int cp = 0; cp < 32; ++cp) {
            uint4 bA = *(const uint4*)&bc[wid][cp][0];  // {as2, ys2, av02, by02}
            uint4 bB = *(const uint4*)&bc[wid][cp][4];  // {av12, by12, av22, by22}
            uint4 wv4 = wAll[cp*64 + lane];
            if (L0) {
                unsigned tv = tA[(cp*64 + lane)*4 + 2];
                oS0 = dot2(bA.x, wv4.x, oS0);
                oS1 = dot2(bA.x, wv4.y, oS1);
                ov0 = dot2(bA.z, wv4.z, dot2(bA.w, tv, ov0));
                ov1 = dot2(bB.x, wv4.z, dot2(bB.y, tv, ov1));
                ov2 = dot2(bB.z, wv4.z, dot2(bB.w, tv, ov2));
            } else {
                uint4 tw = ((const uint4*)tA)[cp*64 + lane];   // {tsa2, tsb2, tv2, pad}
                oS0 = dot2(bA.x, wv4.x, dot2(bA.y, tw.x, oS0));
                oS1 = dot2(bA.x, wv4.y, dot2(bA.y, tw.y, oS1));
                ov0 = dot2(bA.z, wv4.z, dot2(bA.w, tw.z, ov0));
                ov1 = dot2(bB.x, wv4.z, dot2(bB.y, tw.z, ov1));
                ov2 = dot2(bB.z, wv4.z, dot2(bB.w, tw.z, ov2));
                q2s = dot2(bA.y, wv4.w, q2s);
            }
            qv0 = dot2(bA.w, svr[cp], qv0);
            qv1 = dot2(bB.y, svr[cp], qv1);
            qv2 = dot2(bB.w, svr[cp], qv2);
        }
        float gs = silu_(oS0);
        float sg = sigm_(oS1);
        float gv0 = sg*ov0, gv1 = sg*ov1, gv2 = sg*ov2;
        float ns, nv0, nv1, nv2;
        if (L0) {
            ns  = hh*m*gs;
            nv0 = by0 + hh*(m*gv0 + (m-1.f)*qv0);
            nv1 = by1 + hh*(m*gv1 + (m-1.f)*qv1);
            nv2 = by2 + hh*(m*gv2 + (m-1.f)*qv2);
        } else {
            const float* yop = yoldv + (size_t)node*192 + lane*3;
            ns  = 2.f*ys_r + hh*(m*gs + (m-1.f)*q2s);
            nv0 = 2.f*by0 - yop[0] + hh*(m*gv0 + (m-1.f)*qv0);
            nv1 = 2.f*by1 - yop[1] + hh*(m*gv1 + (m-1.f)*qv1);
            nv2 = 2.f*by2 - yop[2] + hh*(m*gv2 + (m-1.f)*qv2);
        }
        if (L0) {
            newS[(size_t)node*64 + lane] = ns;
            float* np = newV + (size_t)node*192 + lane*3;
            np[0] = nv0; np[1] = nv1; np[2] = nv2;
        }
        float p00 = nv0*q0, p01 = nv1*q0, p02 = nv2*q0;
        float p10 = nv0*q1, p11 = nv1*q1, p12 = nv2*q1;
        for (int o = 32; o > 0; o >>= 1) {
            p00 += __shfl_xor(p00, o); p01 += __shfl_xor(p01, o); p02 += __shfl_xor(p02, o);
            p10 += __shfl_xor(p10, o); p11 += __shfl_xor(p11, o); p12 += __shfl_xor(p12, o);
        }
        if (lane == 0) {
            if (L0) {
                pos4out[node] = (float4){p00, p01, p02, 0.f};
            } else {
                float* xp = xout6 + (size_t)node*6;
                xp[0] = p00; xp[1] = p01; xp[2] = p02;
                xp[3] = p10; xp[4] = p11; xp[5] = p12;
            }
        }
    }
}

extern "C" void kernel_launch(void* const* d_in, const int* in_sizes, int n_in,
                              void* d_out, int out_size, void* d_ws, size_t ws_size,
                              hipStream_t stream) {
    const float* x        = (const float*)d_in[0];
    const int*   nattr    = (const int*)  d_in[2];
    const int*   esrc     = (const int*)  d_in[3];
    const int*   edst     = (const int*)  d_in[4];
    const float* embT     = (const float*)d_in[5];
    const float* upM      = (const float*)d_in[6];
    const float* hArr     = (const float*)d_in[7];
    const float* mArr     = (const float*)d_in[8];
    const float* rW1      = (const float*)d_in[9];
    const float* rb1      = (const float*)d_in[10];
    const float* rW2      = (const float*)d_in[11];
    const float* l1s      = (const float*)d_in[12];
    const float* l1v      = (const float*)d_in[13];
    const float* l2s      = (const float*)d_in[14];
    const float* l2v      = (const float*)d_in[15];
    const float* scs      = (const float*)d_in[16];
    const float* scv      = (const float*)d_in[17];
    const float* sis      = (const float*)d_in[18];
    const float* siv      = (const float*)d_in[19];
    int n = in_sizes[0] / 6;
    int e = in_sizes[3];
    float* out = (float*)d_out;

    // ---- workspace carve ----
    float* w = (float*)d_ws;
    float* Q    = w; w += 128;
    float* yAv  = w; w += (size_t)n*192;   // initial y_v (y_old_v for layer 1)
    float* yBs  = w; w += (size_t)n*64;
    float* yBv  = w; w += (size_t)n*192;
    float* aggS = w; w += (size_t)n*64;
    float* aggV = w; w += (size_t)n*192;
    float4* pos4 = (float4*)w; w += (size_t)n*4;
    uint2* mv    = (uint2*)w;  w += (size_t)n*128;           // n*64 uint2
    uint4* Tall  = (uint4*)w;  w += (size_t)2*NATTR*2048*4;  // 2*100*2048 uint4
    unsigned* radTab = (unsigned*)w; w += (size_t)2*(TBINS+1)*64;
    unsigned* siVp = (unsigned*)w; w += (size_t)2*2048;
    uint4* rec = (uint4*)w; w += (size_t)e*4;
    int* cnt   = (int*)w;
    int* offs  = cnt + n;
    int* curG0 = offs + (n + 1);
    int* curG1 = curG0 + n;
    int* acnt  = curG1 + n;
    int* acur  = acnt + NATTR;
    int* nodeOrd = acur + NATTR;
    size_t need = (size_t)((char*)(nodeOrd + n) - (char*)d_ws);
    if (need > ws_size) {
        fprintf(stderr, "kernel_launch: ws too small (%zu > %zu)\n", need, ws_size);
        return;
    }

    const int AGG_GRID  = 1792;  // 7 blocks/CU (20.7 KB LDS)
    const int OC_GRID   = 1024;  // 4 blocks/CU (36 KB LDS)
    const int LIN_GRID  = 2048;
    int eb = (e + 255)/256;
    int nb = (n + 255)/256;

    kQ<<<1, 64, 0, stream>>>(upM, Q);
    hipMemsetAsync(cnt, 0, (size_t)n*sizeof(int), stream);
    hipMemsetAsync(acnt, 0, (size_t)NATTR*sizeof(int), stream);
    kHist<<<eb, 256, 0, stream>>>(edst, cnt, e);
    kScan<<<1, 1024, 0, stream>>>(cnt, offs, curG0, curG1, n);
    kHistA<<<nb, 256, 0, stream>>>(nattr, acnt, n);
    kScanA<<<1, 128, 0, stream>>>(acnt, acur);
    kScatterA<<<nb, 256, 0, stream>>>(nattr, acur, nodeOrd, n);
    kT3<<<dim3(32, 2, 5), 256, 0, stream>>>(embT, scs, scv, (unsigned*)Tall);
    kRadTab<<<dim3(TBINS+1, 2), 64, 0, stream>>>(rW1, rb1, rW2, radTab);
    kPackW<<<dim3(8, 2), 256, 0, stream>>>(siv, siVp);
    kInitLin<<<LIN_GRID, 256, 0, stream>>>(x, Q, l1v, yAv, pos4, mv, n);

    // ---- layer 0 (y_s == 0 analytically) ----
    kGeom<<<eb, 256, 0, stream>>>(pos4, esrc, edst, curG0, rec, e);
    kAgg<0><<<AGG_GRID, 256, 0, stream>>>(rec, mv, offs, curG0, radTab, aggS, aggV, n);
    kOutComb<1><<<OC_GRID, 256, 0, stream>>>(nullptr, yAv, nullptr, aggS, aggV, nattr, nodeOrd,
                                  l2s, l2v, Tall, sis, siVp, Q, hArr, mArr, 0,
                                  yBs, yBv, pos4, out, n);
    // ---- layer 1 ----
    kLin1<<<LIN_GRID, 256, 0, stream>>>(yBs, yBv, l1s + 4096, l1v + 4096, mv, n);
    kGeom<<<eb, 256, 0, stream>>>(pos4, esrc, edst, curG1, rec, e);
    kAgg<1><<<AGG_GRID, 256, 0, stream>>>(rec, mv, offs, curG1,
                                  radTab + (size_t)(TBINS+1)*64, aggS, aggV, n);
    kOutComb<0><<<OC_GRID, 256, 0, stream>>>(yBs, yBv, yAv, aggS, aggV, nattr, nodeOrd,
                                  l2s + (size_t)64*128, l2v + (size_t)64*64,
                                  Tall + (size_t)NATTR*2048,
                                  sis + 4096, siVp + 2048, Q, hArr, mArr, 1,
                                  nullptr, nullptr, nullptr, out, n);
}

// Round 14
// 497.762 us; speedup vs baseline: 1.1481x; 1.1481x over previous
//
#include <hip/hip_runtime.h>
#include <cstdio>
#include <cstdint>

#define CCH 64      // channels C
#define EMBD 32     // embedding dim
#define NBD 8       // num radial basis
#define RHD 32      // radial hidden
#define NATTR 100   // distinct node_attr values
#define TBINS 64    // radial table intervals (65 sample points)

static constexpr float MAXR    = 2.5f;
static constexpr float INVNN   = 0.17677669529663687f;  // 1/sqrt(32)
static constexpr float EFK     = 2.5298221281347035f;   // sqrt(2/2.5)*sqrt(8)
static constexpr float SQRT3   = 1.7320508075688772f;
static constexpr float PI_F    = 3.14159265358979323846f;

typedef __fp16 v2h __attribute__((ext_vector_type(2)));

__device__ __forceinline__ float sigm_(float x) { return 1.f / (1.f + __expf(-x)); }
__device__ __forceinline__ float silu_(float x) { return x / (1.f + __expf(-x)); }
// bf16 helpers
__device__ __forceinline__ unsigned f2bfu(float f) {
    unsigned u = __float_as_uint(f);
    return (u + 0x7FFF + ((u >> 16) & 1)) >> 16;
}
__device__ __forceinline__ unsigned pack2(float lo, float hi) {
    return f2bfu(lo) | (f2bfu(hi) << 16);
}
__device__ __forceinline__ float ulo(unsigned u) { return __uint_as_float(u << 16); }
__device__ __forceinline__ float uhi(unsigned u) { return __uint_as_float(u & 0xFFFF0000u); }
// f16 helpers
__device__ __forceinline__ v2h u2h(unsigned u) { v2h h; __builtin_memcpy(&h, &u, 4); return h; }
__device__ __forceinline__ unsigned pkh(float a, float b) {
    v2h h = __builtin_amdgcn_cvt_pkrtz(a, b);
    unsigned u; __builtin_memcpy(&u, &h, 4); return u;
}
__device__ __forceinline__ unsigned short h1(float f) {
    __fp16 h = (__fp16)f; unsigned short s; __builtin_memcpy(&s, &h, 2); return s;
}
__device__ __forceinline__ float dot2(unsigned a, unsigned b, float c) {
    return __builtin_amdgcn_fdot2(u2h(a), u2h(b), c, false);
}
__device__ __forceinline__ float hlo(unsigned u) { v2h h = u2h(u); return (float)h.x; }
__device__ __forceinline__ float hhi(unsigned u) { v2h h = u2h(u); return (float)h.y; }

// ---------------- Q = polar factor of uplift_M (64x2) ----------------
__global__ void kQ(const float* M, float* Q) {
    int c = threadIdx.x;  // 64 threads = 1 wave
    float m0 = M[2*c], m1 = M[2*c+1];
    float a = m0*m0, b = m0*m1, d = m1*m1;
    for (int o = 32; o > 0; o >>= 1) {
        a += __shfl_xor(a, o); b += __shfl_xor(b, o); d += __shfl_xor(d, o);
    }
    float det = a*d - b*b;
    float s = sqrtf(det);
    float t = sqrtf(a + d + 2.f*s);
    float inv = 1.f / (s*t);
    float i00 = (d + s)*inv, i01 = -b*inv, i11 = (a + s)*inv;
    Q[2*c]   = m0*i00 + m1*i01;
    Q[2*c+1] = m0*i01 + m1*i11;
}

// ---------------- radial table (bf16 pair), INVNN folded in ----------------
__global__ void kRadTab(const float* __restrict__ rW1, const float* __restrict__ rb1,
                        const float* __restrict__ rW2, unsigned* __restrict__ tab) {
    int bin = blockIdx.x;
    int l   = blockIdx.y;
    int lane = threadIdx.x;
    float r = bin * (MAXR / TBINS);
    float safe = fmaxf(r, 1e-9f);
    float invSafe = 1.f / safe;
    float th = PI_F * r * (1.f / MAXR);
    float s0, c0;
    __sincosf(th, &s0, &c0);
    __shared__ float hidS[RHD];
    if (lane < RHD) {
        float hs = rb1[l*RHD + lane];
        float sPrev = 0.f, sCur = s0, twoC = 2.f*c0;
        #pragma unroll
        for (int b = 0; b < NBD; ++b) {
            float efb = EFK * sCur * invSafe;
            hs = fmaf(efb, rW1[(l*NBD + b)*RHD + lane], hs);
            float sN = fmaf(twoC, sCur, -sPrev);
            sPrev = sCur; sCur = sN;
        }
        hidS[lane] = silu_(hs);
    }
    __syncthreads();
    float w1 = 0.f, w2 = 0.f;
    #pragma unroll
    for (int rr = 0; rr < RHD; ++rr) {
        float h = hidS[rr];
        w1 = fmaf(h, rW2[(l*RHD + rr)*128 + lane], w1);
        w2 = fmaf(h, rW2[(l*RHD + rr)*128 + 64 + lane], w2);
    }
    float cut = s0*s0;
    float coef = SQRT3 * cut * invSafe * INVNN;
    tab[((size_t)l*(TBINS+1) + bin)*64 + lane] = pack2(w1*coef, w2*coef);
}

// ---------------- pack siV as f16 channel pairs ----------------
__global__ void kPackW(const float* __restrict__ siv, unsigned* __restrict__ siVp) {
    int l = blockIdx.y;
    int i = blockIdx.x*256 + threadIdx.x;   // 0..2047
    int cp = i >> 6, o = i & 63;
    siVp[l*2048 + i] = pkh(siv[l*4096 + (2*cp)*64 + o], siv[l*4096 + (2*cp+1)*64 + o]);
}

// ---------------- init: y0v, pos4, layer-0 lin1 via dot2 (y0s == 0) ----------------
__global__ __launch_bounds__(256) void kInitLin(const float* __restrict__ x, const float* __restrict__ Qg,
        const float* __restrict__ L1v,
        float* __restrict__ yAv, float4* __restrict__ pos4,
        uint2* __restrict__ mv, int n) {
    __shared__ unsigned wPk[32*64];            // h2(L1v[c][o], L1v[c+1][o]) : 8 KB
    __shared__ __align__(16) unsigned bc[4][32][4];
    int t = threadIdx.x;
    for (int i = t; i < 32*64; i += 256) {
        int cp = i >> 6, o = i & 63;
        wPk[i] = pkh(L1v[(2*cp)*64 + o], L1v[(2*cp+1)*64 + o]);
    }
    __syncthreads();
    int lane = t & 63;
    int wid = t >> 6;
    float q0 = Qg[2*lane], q1 = Qg[2*lane+1];
    for (int node = blockIdx.x*4 + wid; node < n; node += gridDim.x*4) {
        const float* xr = x + (size_t)node*6;
        float x0 = xr[0], x1 = xr[1], x2 = xr[2], x3 = xr[3], x4 = xr[4], x5 = xr[5];
        float y0 = q0*x0 + q1*x3;
        float y1 = q0*x1 + q1*x4;
        float y2 = q0*x2 + q1*x5;
        float* yv = yAv + (size_t)node*192 + lane*3;
        yv[0] = y0; yv[1] = y1; yv[2] = y2;
        if (lane == 0) pos4[node] = (float4){x0, x1, x2, 0.f};
        {
            unsigned short* p = (unsigned short*)bc[wid][lane >> 1];
            int sub = lane & 1;
            p[0*2+sub] = h1(y0); p[1*2+sub] = h1(y1); p[2*2+sub] = h1(y2);
        }
        float a0 = 0.f, a1 = 0.f, a2 = 0.f;
        #pragma unroll 8
        for (int cp = 0; cp < 32; ++cp) {
            uint4 b = *(const uint4*)&bc[wid][cp][0];
            unsigned wp = wPk[cp*64 + lane];
            a0 = dot2(b.x, wp, a0);
            a1 = dot2(b.y, wp, a1);
            a2 = dot2(b.z, wp, a2);
        }
        mv[(size_t)node*64 + lane] = (uint2){ pack2(a0, a1), pack2(a2, 0.f) };
    }
}

// ---------------- CSR degree + offsets (two cursor copies for the 2 kGeom passes) ----------------
__global__ void kHist(const int* dst, int* cnt, int e) {
    int i = blockIdx.x*blockDim.x + threadIdx.x;
    if (i < e) atomicAdd(&cnt[dst[i]], 1);
}

__global__ void kScan(const int* cnt, int* offs, int* curG0, int* curG1, int n) {
    __shared__ int part[1024];
    int t = threadIdx.x;
    int chunk = (n + 1023) >> 10;
    int lo = t*chunk, hi = min(lo + chunk, n);
    int s = 0;
    for (int i = lo; i < hi; ++i) s += cnt[i];
    part[t] = s;
    __syncthreads();
    for (int o = 1; o < 1024; o <<= 1) {
        int w = (t >= o) ? part[t - o] : 0;
        __syncthreads();
        part[t] += w;
        __syncthreads();
    }
    int run = part[t] - s;
    for (int i = lo; i < hi; ++i) {
        int cv = cnt[i];
        offs[i] = run; curG0[i] = run; curG1[i] = run;
        run += cv;
    }
    if (t == 1023) offs[n] = part[1023];
}

// ---------------- geometry + CSR scatter + cut compaction in one pass ----------------
__global__ __launch_bounds__(256) void kGeom(const float4* __restrict__ pos4,
        const int* __restrict__ esrc, const int* __restrict__ edst,
        int* __restrict__ cur, uint4* __restrict__ rec, int e) {
    int i = blockIdx.x*256 + threadIdx.x;
    if (i >= e) return;
    int s = esrc[i], d = edst[i];
    float4 pa = pos4[s], pb = pos4[d];
    float ex = pa.x - pb.x, ey = pa.y - pb.y, ez = pa.z - pb.z;
    float el2 = ex*ex + ey*ey + ez*ez;
    if (el2 >= MAXR*MAXR) return;          // cut == 0: drop the edge entirely
    float elen = sqrtf(el2);
    float u = fminf(elen * ((float)TBINS / MAXR), 63.98f);
    int p = atomicAdd(&cur[d], 1);
    rec[p] = (uint4){ (unsigned)s, pkh(ex, ey), pkh(ez, u), 0u };
}

// ---------------- T tables: interleaved uint4 {tsa2, tsb2, tv2, pad} ----------------
__global__ __launch_bounds__(256) void kT3(const float* __restrict__ embT,
        const float* __restrict__ scs, const float* __restrict__ scv,
        unsigned* __restrict__ TallU) {
    int cp = blockIdx.x, l = blockIdx.y, ag = blockIdx.z;  // 32 x 2 x 5
    int c0 = 2*cp, c1 = c0 + 1;
    __shared__ float sS0[32*128], sS1[32*128], sV0[32*64], sV1[32*64], sE[20*EMBD];
    int t = threadIdx.x;
    const float* p0 = scs + ((size_t)(l*CCH + c0)*EMBD)*128;
    const float* p1 = scs + ((size_t)(l*CCH + c1)*EMBD)*128;
    for (int i = t; i < 32*128; i += 256) { sS0[i] = p0[i]; sS1[i] = p1[i]; }
    const float* q0 = scv + ((size_t)(l*CCH + c0)*EMBD)*64;
    const float* q1 = scv + ((size_t)(l*CCH + c1)*EMBD)*64;
    for (int i = t; i < 32*64; i += 256) { sV0[i] = q0[i]; sV1[i] = q1[i]; }
    const float* eb = embT + (size_t)ag*20*EMBD;
    for (int i = t; i < 20*EMBD; i += 256) sE[i] = eb[i];
    __syncthreads();
    if (t < 128) {
        int o = t;
        for (int a = 0; a < 20; ++a) {
            float acc0 = 0.f, acc1 = 0.f;
            #pragma unroll
            for (int e = 0; e < EMBD; ++e) {
                float ev = sE[a*EMBD + e];
                acc0 = fmaf(ev, sS0[e*128 + o], acc0);
                acc1 = fmaf(ev, sS1[e*128 + o], acc1);
            }
            int aa = ag*20 + a;
            size_t idx = ((size_t)(l*NATTR + aa)*32 + cp)*64 + (o & 63);
            TallU[idx*4 + (o >> 6)] = pkh(acc0, acc1);
        }
    } else if (t < 192) {
        int o = t - 128;
        for (int a = 0; a < 20; ++a) {
            float acc0 = 0.f, acc1 = 0.f;
            #pragma unroll
            for (int e = 0; e < EMBD; ++e) {
                float ev = sE[a*EMBD + e];
                acc0 = fmaf(ev, sV0[e*64 + o], acc0);
                acc1 = fmaf(ev, sV1[e*64 + o], acc1);
            }
            int aa = ag*20 + a;
            size_t idx = ((size_t)(l*NATTR + aa)*32 + cp)*64 + o;
            TallU[idx*4 + 2] = pkh(acc0, acc1);
        }
    }
}

// ---------------- lin1 (layer 1): dot2 ----------------
__global__ __launch_bounds__(256) void kLin1(const float* __restrict__ ys, const float* __restrict__ yv,
        const float* __restrict__ L1s, const float* __restrict__ L1v,
        uint2* __restrict__ mv, int n) {
    __shared__ uint2 wPk[32*64];               // {h2(L1s c,c+1), h2(L1v c,c+1)} : 16 KB
    __shared__ __align__(16) unsigned bc[4][32][4];
    int t = threadIdx.x;
    for (int i = t; i < 32*64; i += 256) {
        int cp = i >> 6, o = i & 63;
        wPk[i] = (uint2){ pkh(L1s[(2*cp)*64 + o], L1s[(2*cp+1)*64 + o]),
                          pkh(L1v[(2*cp)*64 + o], L1v[(2*cp+1)*64 + o]) };
    }
    __syncthreads();
    int lane = t & 63;
    int wid = t >> 6;
    for (int node = blockIdx.x*4 + wid; node < n; node += gridDim.x*4) {
        float ys_r = ys[(size_t)node*64 + lane];
        const float* yvp = yv + (size_t)node*192 + lane*3;
        float y0 = yvp[0], y1 = yvp[1], y2 = yvp[2];
        {
            unsigned short* p = (unsigned short*)bc[wid][lane >> 1];
            int sub = lane & 1;
            p[0*2+sub] = h1(y0); p[1*2+sub] = h1(y1);
            p[2*2+sub] = h1(y2); p[3*2+sub] = h1(ys_r);
        }
        float as = 0.f, a0 = 0.f, a1 = 0.f, a2 = 0.f;
        #pragma unroll 8
        for (int cp = 0; cp < 32; ++cp) {
            uint4 b = *(const uint4*)&bc[wid][cp][0];
            uint2 wp = wPk[cp*64 + lane];
            as = dot2(b.w, wp.x, as);
            a0 = dot2(b.x, wp.y, a0);
            a1 = dot2(b.y, wp.y, a1);
            a2 = dot2(b.z, wp.y, a2);
        }
        mv[(size_t)node*64 + lane] = (uint2){ pack2(a0, a1), pack2(a2, as) };
    }
}

// ---------------- aggregation: compacted records, 2-deep mv prefetch ----------------
template<int WITHV>
__global__ __launch_bounds__(256) void kAgg(const uint4* __restrict__ rec,
        const uint2* __restrict__ mv,
        const int* __restrict__ offs, const int* __restrict__ endA,
        const unsigned* __restrict__ tabG,
        float* __restrict__ aggS, float* __restrict__ aggV, int n) {
    __shared__ unsigned tab[(TBINS+1)*64];   // 16.6 KB bf16 pairs (coef*INVNN folded)
    __shared__ float red[4][64][4];
    int t = threadIdx.x;
    for (int i = t; i < (TBINS+1)*64; i += 256) tab[i] = tabG[i];
    __syncthreads();
    int lane = t & 63;
    int wid = t >> 6;

    for (int node = blockIdx.x; node < n; node += gridDim.x) {
        int beg = offs[node], end = endA[node];
        float accS = 0.f, av0 = 0.f, av1 = 0.f, av2 = 0.f;
        int idx = beg + wid;
        uint4 r0 = (uint4){0u,0u,0u,0u}, r1 = r0;
        uint2 m0 = (uint2){0u,0u}, m1 = m0;
        if (idx < end)     { r0 = rec[idx];   m0 = mv[(size_t)r0.x*64 + lane]; }
        if (idx + 4 < end) { r1 = rec[idx+4]; m1 = mv[(size_t)r1.x*64 + lane]; }
        for (; idx < end; idx += 4) {
            uint4 r2 = (uint4){0u,0u,0u,0u};
            uint2 m2 = (uint2){0u,0u};
            if (idx + 8 < end) { r2 = rec[idx+8]; m2 = mv[(size_t)r2.x*64 + lane]; }
            float ex = hlo(r0.y), ey = hhi(r0.y);
            float ez = hlo(r0.z), u = hhi(r0.z);
            int i0 = (int)u;
            float fr = u - (float)i0;
            unsigned t0 = tab[i0*64 + lane];
            unsigned t1 = tab[i0*64 + 64 + lane];
            float w1 = fmaf(fr, ulo(t1) - ulo(t0), ulo(t0));
            float w2 = fmaf(fr, uhi(t1) - uhi(t0), uhi(t0));
            float dv = ulo(m0.x)*ex + uhi(m0.x)*ey + ulo(m0.y)*ez;
            accS = fmaf(w2, dv, accS);
            if (WITHV) {
                float tt = w1 * uhi(m0.y);
                av0 = fmaf(tt, ex, av0); av1 = fmaf(tt, ey, av1); av2 = fmaf(tt, ez, av2);
            }
            r0 = r1; m0 = m1; r1 = r2; m1 = m2;
        }
        red[wid][lane][0] = accS; red[wid][lane][1] = av0;
        red[wid][lane][2] = av1;  red[wid][lane][3] = av2;
        __syncthreads();
        if (wid == 0) {
            float rs = red[0][lane][0] + red[1][lane][0] + red[2][lane][0] + red[3][lane][0];
            aggS[(size_t)node*64 + lane] = rs;     // INVNN folded into tab
            float r0s = red[0][lane][1] + red[1][lane][1] + red[2][lane][1] + red[3][lane][1];
            float r1s = red[0][lane][2] + red[1][lane][2] + red[2][lane][2] + red[3][lane][2];
            float r2s = red[0][lane][3] + red[1][lane][3] + red[2][lane][3] + red[3][lane][3];
            float* ap = aggV + (size_t)node*192 + lane*3;
            ap[0] = r0s; ap[1] = r1s; ap[2] = r2s;
        }
        __syncthreads();
    }
}

// ---------------- fused out+gating+combine; siS/siV in regs, 28 KB LDS, tw prefetch ----------------
template<int L0>
__global__ __launch_bounds__(256) void kOutComb(const float* __restrict__ ys, const float* __restrict__ yv,
        const float* __restrict__ yoldv,
        const float* __restrict__ aggS, const float* __restrict__ aggV, const int* __restrict__ attr,
        const float* __restrict__ L2s, const float* __restrict__ L2v,
        const uint4* __restrict__ Tall,
        const unsigned* __restrict__ siSp, const unsigned* __restrict__ siVp, const float* __restrict__ Qg,
        const float* __restrict__ hArr, const float* __restrict__ mArr, int li,
        float* __restrict__ newS, float* __restrict__ newV,
        float4* __restrict__ pos4out, float* __restrict__ xout6, int n) {
    __shared__ uint2 wAB[32*64];     // {h2(L2s a), h2(L2s b)} : 16 KB
    __shared__ unsigned wLv[32*64];  // h2(L2v) : 8 KB
    __shared__ __align__(16) unsigned bc[4][32][8];  // 4 KB
    int t = threadIdx.x;
    for (int i = t; i < 32*64; i += 256) {
        int cp = i >> 6, o = i & 63;
        wAB[i] = (uint2){ pkh(L2s[(2*cp)*128 + o],      L2s[(2*cp+1)*128 + o]),
                          pkh(L2s[(2*cp)*128 + 64 + o], L2s[(2*cp+1)*128 + 64 + o]) };
        wLv[i] = pkh(L2v[(2*cp)*64 + o], L2v[(2*cp+1)*64 + o]);
    }
    __syncthreads();
    int lane = t & 63;
    int wid = t >> 6;
    // node-invariant si weights -> registers
    unsigned svr[32], ssr[32];
    #pragma unroll
    for (int cp = 0; cp < 32; ++cp) {
        svr[cp] = siVp[cp*64 + lane];
        ssr[cp] = L0 ? 0u : siSp[cp*64 + lane];
    }
    float hh = hArr[li]; hh *= hh;
    float m = mArr[li];
    float q0 = Qg[2*lane], q1 = Qg[2*lane+1];
    for (int node = blockIdx.x*4 + wid; node < n; node += gridDim.x*4) {
        int a = attr[node];
        const unsigned* tA = (const unsigned*)(Tall + (size_t)a*2048);
        float as_r = aggS[(size_t)node*64 + lane];
        float ys_r = L0 ? 0.f : ys[(size_t)node*64 + lane];
        const float* avp = aggV + (size_t)node*192 + lane*3;
        float av0 = avp[0], av1 = avp[1], av2 = avp[2];
        const float* yvp = yv + (size_t)node*192 + lane*3;
        float by0 = yvp[0], by1 = yvp[1], by2 = yvp[2];
        {
            unsigned short* p = (unsigned short*)bc[wid][lane >> 1];
            int sub = lane & 1;
            p[0*2+sub] = h1(as_r); p[1*2+sub] = L0 ? (unsigned short)0 : h1(ys_r);
            p[2*2+sub] = h1(av0);  p[3*2+sub] = h1(by0);
            p[4*2+sub] = h1(av1);  p[5*2+sub] = h1(by1);
            p[6*2+sub] = h1(av2);  p[7*2+sub] = h1(by2);
        }
        float oS0=0.f, oS1=0.f, ov0=0.f, ov1=0.f, ov2=0.f;
        float q2s=0.f, qv0=0.f, qv1=0.f, qv2=0.f;
        // 1-iter software prefetch of the Tall load (L2-hit latency ~200 cyc)
        uint4 tw; unsigned tv;
        if (L0) tv = tA[lane*4 + 2];
        else    tw = ((const uint4*)tA)[lane];
        #pragma unroll 4
        for (int cp = 0; cp < 32; ++cp) {
            uint4 twN; unsigned tvN;
            if (cp < 31) {
                if (L0) tvN = tA[((cp+1)*64 + lane)*4 + 2];
                else    twN = ((const uint4*)tA)[(cp+1)*64 + lane];
            }
            uint4 bA = *(const uint4*)&bc[wid][cp][0];  // {as2, ys2, av02, by02}
            uint4 bB = *(const uint4*)&bc[wid][cp][4];  // {av12, by12, av22, by22}
            uint2 ab = wAB[cp*64 + lane];
            unsigned lv = wLv[cp*64 + lane];
            if (L0) {
                oS0 = dot2(bA.x, ab.x, oS0);
                oS1 = dot2(bA.x, ab.y, oS1);
                ov0 = dot2(bA.z, lv, dot2(bA.w, tv, ov0));
                ov1 = dot2(bB.x, lv, dot2(bB.y, tv, ov1));
                ov2 = dot2(bB.z, lv, dot2(bB.w, tv, ov2));
            } else {
                oS0 = dot2(bA.x, ab.x, dot2(bA.y, tw.x, oS0));
                oS1 = dot2(bA.x, ab.y, dot2(bA.y, tw.y, oS1));
                ov0 = dot2(bA.z, lv, dot2(bA.w, tw.z, ov0));
                ov1 = dot2(bB.x, lv, dot2(bB.y, tw.z, ov1));
                ov2 = dot2(bB.z, lv, dot2(bB.w, tw.z, ov2));
                q2s = dot2(bA.y, ssr[cp], q2s);
            }
            qv0 = dot2(bA.w, svr[cp], qv0);
            qv1 = dot2(bB.y, svr[cp], qv1);
            qv2 = dot2(bB.w, svr[cp], qv2);
            if (L0) tv = tvN; else tw = twN;
        }
        float gs = silu_(oS0);
        float sg = sigm_(oS1);
        float gv0 = sg*ov0, gv1 = sg*ov1, gv2 = sg*ov2;
        float ns, nv0, nv1, nv2;
        if (L0) {
            ns  = hh*m*gs;
            nv0 = by0 + hh*(m*gv0 + (m-1.f)*qv0);
            nv1 = by1 + hh*(m*gv1 + (m-1.f)*qv1);
            nv2 = by2 + hh*(m*gv2 + (m-1.f)*qv2);
        } else {
            const float* yop = yoldv + (size_t)node*192 + lane*3;
            ns  = 2.f*ys_r + hh*(m*gs + (m-1.f)*q2s);
            nv0 = 2.f*by0 - yop[0] + hh*(m*gv0 + (m-1.f)*qv0);
            nv1 = 2.f*by1 - yop[1] + hh*(m*gv1 + (m-1.f)*qv1);
            nv2 = 2.f*by2 - yop[2] + hh*(m*gv2 + (m-1.f)*qv2);
        }
        if (L0) {
            newS[(size_t)node*64 + lane] = ns;
            float* np = newV + (size_t)node*192 + lane*3;
            np[0] = nv0; np[1] = nv1; np[2] = nv2;
        }
        float p00 = nv0*q0, p01 = nv1*q0, p02 = nv2*q0;
        float p10 = nv0*q1, p11 = nv1*q1, p12 = nv2*q1;
        for (int o = 32; o > 0; o >>= 1) {
            p00 += __shfl_xor(p00, o); p01 += __shfl_xor(p01, o); p02 += __shfl_xor(p02, o);
            p10 += __shfl_xor(p10, o); p11 += __shfl_xor(p11, o); p12 += __shfl_xor(p12, o);
        }
        if (lane == 0) {
            if (L0) {
                pos4out[node] = (float4){p00, p01, p02, 0.f};
            } else {
                float* xp = xout6 + (size_t)node*6;
                xp[0] = p00; xp[1] = p01; xp[2] = p02;
                xp[3] = p10; xp[4] = p11; xp[5] = p12;
            }
        }
    }
}

extern "C" void kernel_launch(void* const* d_in, const int* in_sizes, int n_in,
                              void* d_out, int out_size, void* d_ws, size_t ws_size,
                              hipStream_t stream) {
    const float* x        = (const float*)d_in[0];
    const int*   nattr    = (const int*)  d_in[2];
    const int*   esrc     = (const int*)  d_in[3];
    const int*   edst     = (const int*)  d_in[4];
    const float* embT     = (const float*)d_in[5];
    const float* upM      = (const float*)d_in[6];
    const float* hArr     = (const float*)d_in[7];
    const float* mArr     = (const float*)d_in[8];
    const float* rW1      = (const float*)d_in[9];
    const float* rb1      = (const float*)d_in[10];
    const float* rW2      = (const float*)d_in[11];
    const float* l1s      = (const float*)d_in[12];
    const float* l1v      = (const float*)d_in[13];
    const float* l2s      = (const float*)d_in[14];
    const float* l2v      = (const float*)d_in[15];
    const float* scs      = (const float*)d_in[16];
    const float* scv      = (const float*)d_in[17];
    const float* sis      = (const float*)d_in[18];
    const float* siv      = (const float*)d_in[19];
    int n = in_sizes[0] / 6;
    int e = in_sizes[3];
    float* out = (float*)d_out;

    // ---- workspace carve ----
    float* w = (float*)d_ws;
    float* Q    = w; w += 128;
    float* yAv  = w; w += (size_t)n*192;   // initial y_v (y_old_v for layer 1)
    float* yBs  = w; w += (size_t)n*64;
    float* yBv  = w; w += (size_t)n*192;
    float* aggS = w; w += (size_t)n*64;
    float* aggV = w; w += (size_t)n*192;
    float4* pos4 = (float4*)w; w += (size_t)n*4;
    uint2* mv    = (uint2*)w;  w += (size_t)n*128;           // n*64 uint2
    uint4* Tall  = (uint4*)w;  w += (size_t)2*NATTR*2048*4;  // 2*100*2048 uint4
    unsigned* radTab = (unsigned*)w; w += (size_t)2*(TBINS+1)*64;
    unsigned* siVp = (unsigned*)w; w += (size_t)2*2048;
    unsigned* siSp = (unsigned*)w; w += (size_t)2*2048;
    uint4* rec = (uint4*)w; w += (size_t)e*4;
    int* cnt   = (int*)w;
    int* offs  = cnt + n;
    int* curG0 = offs + (n + 1);
    int* curG1 = curG0 + n;
    size_t need = (size_t)((char*)(curG1 + n) - (char*)d_ws);
    if (need > ws_size) {
        fprintf(stderr, "kernel_launch: ws too small (%zu > %zu)\n", need, ws_size);
        return;
    }

    const int AGG_GRID  = 1792;  // 7 blocks/CU (20.7 KB LDS)
    const int OC_GRID   = 1280;  // 5 blocks/CU (28 KB LDS)
    const int LIN_GRID  = 2048;
    int eb = (e + 255)/256;

    kQ<<<1, 64, 0, stream>>>(upM, Q);
    hipMemsetAsync(cnt, 0, (size_t)n*sizeof(int), stream);
    kHist<<<eb, 256, 0, stream>>>(edst, cnt, e);
    kScan<<<1, 1024, 0, stream>>>(cnt, offs, curG0, curG1, n);
    kT3<<<dim3(32, 2, 5), 256, 0, stream>>>(embT, scs, scv, (unsigned*)Tall);
    kRadTab<<<dim3(TBINS+1, 2), 64, 0, stream>>>(rW1, rb1, rW2, radTab);
    kPackW<<<dim3(8, 2), 256, 0, stream>>>(siv, siVp);
    kPackW<<<dim3(8, 2), 256, 0, stream>>>(sis, siSp);
    kInitLin<<<LIN_GRID, 256, 0, stream>>>(x, Q, l1v, yAv, pos4, mv, n);

    // ---- layer 0 (y_s == 0 analytically) ----
    kGeom<<<eb, 256, 0, stream>>>(pos4, esrc, edst, curG0, rec, e);
    kAgg<0><<<AGG_GRID, 256, 0, stream>>>(rec, mv, offs, curG0, radTab, aggS, aggV, n);
    kOutComb<1><<<OC_GRID, 256, 0, stream>>>(nullptr, yAv, nullptr, aggS, aggV, nattr,
                                  l2s, l2v, Tall, siSp, siVp, Q, hArr, mArr, 0,
                                  yBs, yBv, pos4, out, n);
    // ---- layer 1 ----
    kLin1<<<LIN_GRID, 256, 0, stream>>>(yBs, yBv, l1s + 4096, l1v + 4096, mv, n);
    kGeom<<<eb, 256, 0, stream>>>(pos4, esrc, edst, curG1, rec, e);
    kAgg<1><<<AGG_GRID, 256, 0, stream>>>(rec, mv, offs, curG1,
                                  radTab + (size_t)(TBINS+1)*64, aggS, aggV, n);
    kOutComb<0><<<OC_GRID, 256, 0, stream>>>(yBs, yBv, yAv, aggS, aggV, nattr,
                                  l2s + (size_t)64*128, l2v + (size_t)64*64,
                                  Tall + (size_t)NATTR*2048,
                                  siSp + 2048, siVp + 2048, Q, hArr, mArr, 1,
                                  nullptr, nullptr, nullptr, out, n);
}

// Round 15
// 486.330 us; speedup vs baseline: 1.1751x; 1.0235x over previous
//
#include <hip/hip_runtime.h>
#include <cstdio>
#include <cstdint>

#define CCH 64      // channels C
#define EMBD 32     // embedding dim
#define NBD 8       // num radial basis
#define RHD 32      // radial hidden
#define NATTR 100   // distinct node_attr values
#define TBINS 64    // radial table intervals (65 sample points)

static constexpr float MAXR    = 2.5f;
static constexpr float INVNN   = 0.17677669529663687f;  // 1/sqrt(32)
static constexpr float EFK     = 2.5298221281347035f;   // sqrt(2/2.5)*sqrt(8)
static constexpr float SQRT3   = 1.7320508075688772f;
static constexpr float PI_F    = 3.14159265358979323846f;

typedef __fp16 v2h __attribute__((ext_vector_type(2)));

__device__ __forceinline__ float sigm_(float x) { return 1.f / (1.f + __expf(-x)); }
__device__ __forceinline__ float silu_(float x) { return x / (1.f + __expf(-x)); }
// bf16 helpers
__device__ __forceinline__ unsigned f2bfu(float f) {
    unsigned u = __float_as_uint(f);
    return (u + 0x7FFF + ((u >> 16) & 1)) >> 16;
}
__device__ __forceinline__ unsigned pack2(float lo, float hi) {
    return f2bfu(lo) | (f2bfu(hi) << 16);
}
__device__ __forceinline__ float ulo(unsigned u) { return __uint_as_float(u << 16); }
__device__ __forceinline__ float uhi(unsigned u) { return __uint_as_float(u & 0xFFFF0000u); }
// f16 helpers
__device__ __forceinline__ v2h u2h(unsigned u) { v2h h; __builtin_memcpy(&h, &u, 4); return h; }
__device__ __forceinline__ unsigned pkh(float a, float b) {
    v2h h = __builtin_amdgcn_cvt_pkrtz(a, b);
    unsigned u; __builtin_memcpy(&u, &h, 4); return u;
}
__device__ __forceinline__ unsigned short h1(float f) {
    __fp16 h = (__fp16)f; unsigned short s; __builtin_memcpy(&s, &h, 2); return s;
}
__device__ __forceinline__ float dot2(unsigned a, unsigned b, float c) {
    return __builtin_amdgcn_fdot2(u2h(a), u2h(b), c, false);
}
__device__ __forceinline__ float hlo(unsigned u) { v2h h = u2h(u); return (float)h.x; }
__device__ __forceinline__ float hhi(unsigned u) { v2h h = u2h(u); return (float)h.y; }

// ---------------- Q = polar factor of uplift_M (64x2) ----------------
__global__ void kQ(const float* M, float* Q) {
    int c = threadIdx.x;  // 64 threads = 1 wave
    float m0 = M[2*c], m1 = M[2*c+1];
    float a = m0*m0, b = m0*m1, d = m1*m1;
    for (int o = 32; o > 0; o >>= 1) {
        a += __shfl_xor(a, o); b += __shfl_xor(b, o); d += __shfl_xor(d, o);
    }
    float det = a*d - b*b;
    float s = sqrtf(det);
    float t = sqrtf(a + d + 2.f*s);
    float inv = 1.f / (s*t);
    float i00 = (d + s)*inv, i01 = -b*inv, i11 = (a + s)*inv;
    Q[2*c]   = m0*i00 + m1*i01;
    Q[2*c+1] = m0*i01 + m1*i11;
}

// ---------------- radial table (bf16 pair), INVNN folded in ----------------
__global__ void kRadTab(const float* __restrict__ rW1, const float* __restrict__ rb1,
                        const float* __restrict__ rW2, unsigned* __restrict__ tab) {
    int bin = blockIdx.x;
    int l   = blockIdx.y;
    int lane = threadIdx.x;
    float r = bin * (MAXR / TBINS);
    float safe = fmaxf(r, 1e-9f);
    float invSafe = 1.f / safe;
    float th = PI_F * r * (1.f / MAXR);
    float s0, c0;
    __sincosf(th, &s0, &c0);
    __shared__ float hidS[RHD];
    if (lane < RHD) {
        float hs = rb1[l*RHD + lane];
        float sPrev = 0.f, sCur = s0, twoC = 2.f*c0;
        #pragma unroll
        for (int b = 0; b < NBD; ++b) {
            float efb = EFK * sCur * invSafe;
            hs = fmaf(efb, rW1[(l*NBD + b)*RHD + lane], hs);
            float sN = fmaf(twoC, sCur, -sPrev);
            sPrev = sCur; sCur = sN;
        }
        hidS[lane] = silu_(hs);
    }
    __syncthreads();
    float w1 = 0.f, w2 = 0.f;
    #pragma unroll
    for (int rr = 0; rr < RHD; ++rr) {
        float h = hidS[rr];
        w1 = fmaf(h, rW2[(l*RHD + rr)*128 + lane], w1);
        w2 = fmaf(h, rW2[(l*RHD + rr)*128 + 64 + lane], w2);
    }
    float cut = s0*s0;
    float coef = SQRT3 * cut * invSafe * INVNN;
    tab[((size_t)l*(TBINS+1) + bin)*64 + lane] = pack2(w1*coef, w2*coef);
}

// ---------------- pack siV as f16 channel pairs ----------------
__global__ void kPackW(const float* __restrict__ siv, unsigned* __restrict__ siVp) {
    int l = blockIdx.y;
    int i = blockIdx.x*256 + threadIdx.x;   // 0..2047
    int cp = i >> 6, o = i & 63;
    siVp[l*2048 + i] = pkh(siv[l*4096 + (2*cp)*64 + o], siv[l*4096 + (2*cp+1)*64 + o]);
}

// ---------------- init: y0v, pos4, layer-0 lin1 via dot2 (y0s == 0) ----------------
__global__ __launch_bounds__(256) void kInitLin(const float* __restrict__ x, const float* __restrict__ Qg,
        const float* __restrict__ L1v,
        float* __restrict__ yAv, float4* __restrict__ pos4,
        uint2* __restrict__ mv, int n) {
    __shared__ unsigned wPk[32*64];            // h2(L1v[c][o], L1v[c+1][o]) : 8 KB
    __shared__ __align__(16) unsigned bc[4][32][4];
    int t = threadIdx.x;
    for (int i = t; i < 32*64; i += 256) {
        int cp = i >> 6, o = i & 63;
        wPk[i] = pkh(L1v[(2*cp)*64 + o], L1v[(2*cp+1)*64 + o]);
    }
    __syncthreads();
    int lane = t & 63;
    int wid = t >> 6;
    float q0 = Qg[2*lane], q1 = Qg[2*lane+1];
    for (int node = blockIdx.x*4 + wid; node < n; node += gridDim.x*4) {
        const float* xr = x + (size_t)node*6;
        float x0 = xr[0], x1 = xr[1], x2 = xr[2], x3 = xr[3], x4 = xr[4], x5 = xr[5];
        float y0 = q0*x0 + q1*x3;
        float y1 = q0*x1 + q1*x4;
        float y2 = q0*x2 + q1*x5;
        float* yv = yAv + (size_t)node*192 + lane*3;
        yv[0] = y0; yv[1] = y1; yv[2] = y2;
        if (lane == 0) pos4[node] = (float4){x0, x1, x2, 0.f};
        {
            unsigned short* p = (unsigned short*)bc[wid][lane >> 1];
            int sub = lane & 1;
            p[0*2+sub] = h1(y0); p[1*2+sub] = h1(y1); p[2*2+sub] = h1(y2);
        }
        float a0 = 0.f, a1 = 0.f, a2 = 0.f;
        #pragma unroll 8
        for (int cp = 0; cp < 32; ++cp) {
            uint4 b = *(const uint4*)&bc[wid][cp][0];
            unsigned wp = wPk[cp*64 + lane];
            a0 = dot2(b.x, wp, a0);
            a1 = dot2(b.y, wp, a1);
            a2 = dot2(b.z, wp, a2);
        }
        mv[(size_t)node*64 + lane] = (uint2){ pack2(a0, a1), pack2(a2, 0.f) };
    }
}

// ---------------- CSR degree + offsets (two cursor copies for the 2 kGeom passes) ----------------
__global__ void kHist(const int* dst, int* cnt, int e) {
    int i = blockIdx.x*blockDim.x + threadIdx.x;
    if (i < e) atomicAdd(&cnt[dst[i]], 1);
}

__global__ void kScan(const int* cnt, int* offs, int* curG0, int* curG1, int n) {
    __shared__ int part[1024];
    int t = threadIdx.x;
    int chunk = (n + 1023) >> 10;
    int lo = t*chunk, hi = min(lo + chunk, n);
    int s = 0;
    for (int i = lo; i < hi; ++i) s += cnt[i];
    part[t] = s;
    __syncthreads();
    for (int o = 1; o < 1024; o <<= 1) {
        int w = (t >= o) ? part[t - o] : 0;
        __syncthreads();
        part[t] += w;
        __syncthreads();
    }
    int run = part[t] - s;
    for (int i = lo; i < hi; ++i) {
        int cv = cnt[i];
        offs[i] = run; curG0[i] = run; curG1[i] = run;
        run += cv;
    }
    if (t == 1023) offs[n] = part[1023];
}

// ---------------- geometry + CSR scatter + cut compaction in one pass ----------------
__global__ __launch_bounds__(256) void kGeom(const float4* __restrict__ pos4,
        const int* __restrict__ esrc, const int* __restrict__ edst,
        int* __restrict__ cur, uint4* __restrict__ rec, int e) {
    int i = blockIdx.x*256 + threadIdx.x;
    if (i >= e) return;
    int s = esrc[i], d = edst[i];
    float4 pa = pos4[s], pb = pos4[d];
    float ex = pa.x - pb.x, ey = pa.y - pb.y, ez = pa.z - pb.z;
    float el2 = ex*ex + ey*ey + ez*ez;
    if (el2 >= MAXR*MAXR) return;          // cut == 0: drop the edge entirely
    float elen = sqrtf(el2);
    float u = fminf(elen * ((float)TBINS / MAXR), 63.98f);
    int p = atomicAdd(&cur[d], 1);
    rec[p] = (uint4){ (unsigned)s, pkh(ex, ey), pkh(ez, u), 0u };
}

// ---------------- T tables: interleaved uint4 {tsa2, tsb2, tv2, pad} ----------------
__global__ __launch_bounds__(256) void kT3(const float* __restrict__ embT,
        const float* __restrict__ scs, const float* __restrict__ scv,
        unsigned* __restrict__ TallU) {
    int cp = blockIdx.x, l = blockIdx.y, ag = blockIdx.z;  // 32 x 2 x 5
    int c0 = 2*cp, c1 = c0 + 1;
    __shared__ float sS0[32*128], sS1[32*128], sV0[32*64], sV1[32*64], sE[20*EMBD];
    int t = threadIdx.x;
    const float* p0 = scs + ((size_t)(l*CCH + c0)*EMBD)*128;
    const float* p1 = scs + ((size_t)(l*CCH + c1)*EMBD)*128;
    for (int i = t; i < 32*128; i += 256) { sS0[i] = p0[i]; sS1[i] = p1[i]; }
    const float* q0 = scv + ((size_t)(l*CCH + c0)*EMBD)*64;
    const float* q1 = scv + ((size_t)(l*CCH + c1)*EMBD)*64;
    for (int i = t; i < 32*64; i += 256) { sV0[i] = q0[i]; sV1[i] = q1[i]; }
    const float* eb = embT + (size_t)ag*20*EMBD;
    for (int i = t; i < 20*EMBD; i += 256) sE[i] = eb[i];
    __syncthreads();
    if (t < 128) {
        int o = t;
        for (int a = 0; a < 20; ++a) {
            float acc0 = 0.f, acc1 = 0.f;
            #pragma unroll
            for (int e = 0; e < EMBD; ++e) {
                float ev = sE[a*EMBD + e];
                acc0 = fmaf(ev, sS0[e*128 + o], acc0);
                acc1 = fmaf(ev, sS1[e*128 + o], acc1);
            }
            int aa = ag*20 + a;
            size_t idx = ((size_t)(l*NATTR + aa)*32 + cp)*64 + (o & 63);
            TallU[idx*4 + (o >> 6)] = pkh(acc0, acc1);
        }
    } else if (t < 192) {
        int o = t - 128;
        for (int a = 0; a < 20; ++a) {
            float acc0 = 0.f, acc1 = 0.f;
            #pragma unroll
            for (int e = 0; e < EMBD; ++e) {
                float ev = sE[a*EMBD + e];
                acc0 = fmaf(ev, sV0[e*64 + o], acc0);
                acc1 = fmaf(ev, sV1[e*64 + o], acc1);
            }
            int aa = ag*20 + a;
            size_t idx = ((size_t)(l*NATTR + aa)*32 + cp)*64 + o;
            TallU[idx*4 + 2] = pkh(acc0, acc1);
        }
    }
}

// ---------------- lin1 (layer 1): dot2 ----------------
__global__ __launch_bounds__(256) void kLin1(const float* __restrict__ ys, const float* __restrict__ yv,
        const float* __restrict__ L1s, const float* __restrict__ L1v,
        uint2* __restrict__ mv, int n) {
    __shared__ uint2 wPk[32*64];               // {h2(L1s c,c+1), h2(L1v c,c+1)} : 16 KB
    __shared__ __align__(16) unsigned bc[4][32][4];
    int t = threadIdx.x;
    for (int i = t; i < 32*64; i += 256) {
        int cp = i >> 6, o = i & 63;
        wPk[i] = (uint2){ pkh(L1s[(2*cp)*64 + o], L1s[(2*cp+1)*64 + o]),
                          pkh(L1v[(2*cp)*64 + o], L1v[(2*cp+1)*64 + o]) };
    }
    __syncthreads();
    int lane = t & 63;
    int wid = t >> 6;
    for (int node = blockIdx.x*4 + wid; node < n; node += gridDim.x*4) {
        float ys_r = ys[(size_t)node*64 + lane];
        const float* yvp = yv + (size_t)node*192 + lane*3;
        float y0 = yvp[0], y1 = yvp[1], y2 = yvp[2];
        {
            unsigned short* p = (unsigned short*)bc[wid][lane >> 1];
            int sub = lane & 1;
            p[0*2+sub] = h1(y0); p[1*2+sub] = h1(y1);
            p[2*2+sub] = h1(y2); p[3*2+sub] = h1(ys_r);
        }
        float as = 0.f, a0 = 0.f, a1 = 0.f, a2 = 0.f;
        #pragma unroll 8
        for (int cp = 0; cp < 32; ++cp) {
            uint4 b = *(const uint4*)&bc[wid][cp][0];
            uint2 wp = wPk[cp*64 + lane];
            as = dot2(b.w, wp.x, as);
            a0 = dot2(b.x, wp.y, a0);
            a1 = dot2(b.y, wp.y, a1);
            a2 = dot2(b.z, wp.y, a2);
        }
        mv[(size_t)node*64 + lane] = (uint2){ pack2(a0, a1), pack2(a2, as) };
    }
}

// ---------------- aggregation: compacted records, 2-deep mv prefetch ----------------
template<int WITHV>
__global__ __launch_bounds__(256) void kAgg(const uint4* __restrict__ rec,
        const uint2* __restrict__ mv,
        const int* __restrict__ offs, const int* __restrict__ endA,
        const unsigned* __restrict__ tabG,
        float* __restrict__ aggS, float* __restrict__ aggV, int n) {
    __shared__ unsigned tab[(TBINS+1)*64];   // 16.6 KB bf16 pairs (coef*INVNN folded)
    __shared__ float red[4][64][4];
    int t = threadIdx.x;
    for (int i = t; i < (TBINS+1)*64; i += 256) tab[i] = tabG[i];
    __syncthreads();
    int lane = t & 63;
    int wid = t >> 6;

    for (int node = blockIdx.x; node < n; node += gridDim.x) {
        int beg = offs[node], end = endA[node];
        float accS = 0.f, av0 = 0.f, av1 = 0.f, av2 = 0.f;
        int idx = beg + wid;
        uint4 r0 = (uint4){0u,0u,0u,0u}, r1 = r0;
        uint2 m0 = (uint2){0u,0u}, m1 = m0;
        if (idx < end)     { r0 = rec[idx];   m0 = mv[(size_t)r0.x*64 + lane]; }
        if (idx + 4 < end) { r1 = rec[idx+4]; m1 = mv[(size_t)r1.x*64 + lane]; }
        for (; idx < end; idx += 4) {
            uint4 r2 = (uint4){0u,0u,0u,0u};
            uint2 m2 = (uint2){0u,0u};
            if (idx + 8 < end) { r2 = rec[idx+8]; m2 = mv[(size_t)r2.x*64 + lane]; }
            float ex = hlo(r0.y), ey = hhi(r0.y);
            float ez = hlo(r0.z), u = hhi(r0.z);
            int i0 = (int)u;
            float fr = u - (float)i0;
            unsigned t0 = tab[i0*64 + lane];
            unsigned t1 = tab[i0*64 + 64 + lane];
            float w1 = fmaf(fr, ulo(t1) - ulo(t0), ulo(t0));
            float w2 = fmaf(fr, uhi(t1) - uhi(t0), uhi(t0));
            float dv = ulo(m0.x)*ex + uhi(m0.x)*ey + ulo(m0.y)*ez;
            accS = fmaf(w2, dv, accS);
            if (WITHV) {
                float tt = w1 * uhi(m0.y);
                av0 = fmaf(tt, ex, av0); av1 = fmaf(tt, ey, av1); av2 = fmaf(tt, ez, av2);
            }
            r0 = r1; m0 = m1; r1 = r2; m1 = m2;
        }
        red[wid][lane][0] = accS; red[wid][lane][1] = av0;
        red[wid][lane][2] = av1;  red[wid][lane][3] = av2;
        __syncthreads();
        if (wid == 0) {
            float rs = red[0][lane][0] + red[1][lane][0] + red[2][lane][0] + red[3][lane][0];
            aggS[(size_t)node*64 + lane] = rs;     // INVNN folded into tab
            float r0s = red[0][lane][1] + red[1][lane][1] + red[2][lane][1] + red[3][lane][1];
            float r1s = red[0][lane][2] + red[1][lane][2] + red[2][lane][2] + red[3][lane][2];
            float r2s = red[0][lane][3] + red[1][lane][3] + red[2][lane][3] + red[3][lane][3];
            float* ap = aggV + (size_t)node*192 + lane*3;
            ap[0] = r0s; ap[1] = r1s; ap[2] = r2s;
        }
        __syncthreads();
    }
}

// ---------------- fused out+gating+combine; fully-unrolled channel loop ----------------
template<int L0>
__global__ __launch_bounds__(256) void kOutComb(const float* __restrict__ ys, const float* __restrict__ yv,
        const float* __restrict__ yoldv,
        const float* __restrict__ aggS, const float* __restrict__ aggV, const int* __restrict__ attr,
        const float* __restrict__ L2s, const float* __restrict__ L2v,
        const uint4* __restrict__ Tall,
        const float* __restrict__ siS, const unsigned* __restrict__ siVp, const float* __restrict__ Qg,
        const float* __restrict__ hArr, const float* __restrict__ mArr, int li,
        float* __restrict__ newS, float* __restrict__ newV,
        float4* __restrict__ pos4out, float* __restrict__ xout6, int n) {
    __shared__ uint4 wAll[32*64];    // {h2(L2s a), h2(L2s b), h2(L2v), h2(siS)} : 32 KB
    __shared__ __align__(16) unsigned bc[4][32][8];  // 4 KB
    int t = threadIdx.x;
    for (int i = t; i < 32*64; i += 256) {
        int cp = i >> 6, o = i & 63;
        wAll[i] = (uint4){ pkh(L2s[(2*cp)*128 + o],      L2s[(2*cp+1)*128 + o]),
                           pkh(L2s[(2*cp)*128 + 64 + o], L2s[(2*cp+1)*128 + 64 + o]),
                           pkh(L2v[(2*cp)*64 + o], L2v[(2*cp+1)*64 + o]),
                           L0 ? 0u : pkh(siS[(2*cp)*64 + o], siS[(2*cp+1)*64 + o]) };
    }
    __syncthreads();
    int lane = t & 63;
    int wid = t >> 6;
    // node-invariant siV pack -> registers (full unroll keeps indices constant)
    unsigned svr[32];
    #pragma unroll
    for (int cp = 0; cp < 32; ++cp) svr[cp] = siVp[cp*64 + lane];
    float hh = hArr[li]; hh *= hh;
    float m = mArr[li];
    float q0 = Qg[2*lane], q1 = Qg[2*lane+1];
    for (int node = blockIdx.x*4 + wid; node < n; node += gridDim.x*4) {
        int a = attr[node];
        const unsigned* tA = (const unsigned*)(Tall + (size_t)a*2048);
        float as_r = aggS[(size_t)node*64 + lane];
        float ys_r = L0 ? 0.f : ys[(size_t)node*64 + lane];
        const float* avp = aggV + (size_t)node*192 + lane*3;
        float av0 = avp[0], av1 = avp[1], av2 = avp[2];
        const float* yvp = yv + (size_t)node*192 + lane*3;
        float by0 = yvp[0], by1 = yvp[1], by2 = yvp[2];
        {
            unsigned short* p = (unsigned short*)bc[wid][lane >> 1];
            int sub = lane & 1;
            p[0*2+sub] = h1(as_r); p[1*2+sub] = L0 ? (unsigned short)0 : h1(ys_r);
            p[2*2+sub] = h1(av0);  p[3*2+sub] = h1(by0);
            p[4*2+sub] = h1(av1);  p[5*2+sub] = h1(by1);
            p[6*2+sub] = h1(av2);  p[7*2+sub] = h1(by2);
        }
        float oS0=0.f, oS1=0.f, ov0=0.f, ov1=0.f, ov2=0.f;
        float q2s=0.f, qv0=0.f, qv1=0.f, qv2=0.f;
        #pragma unroll
        for (int cp = 0; cp < 32; ++cp) {
            uint4 bA = *(const uint4*)&bc[wid][cp][0];  // {as2, ys2, av02, by02}
            uint4 bB = *(const uint4*)&bc[wid][cp][4];  // {av12, by12, av22, by22}
            uint4 wv4 = wAll[cp*64 + lane];
            if (L0) {
                unsigned tv = tA[(cp*64 + lane)*4 + 2];
                oS0 = dot2(bA.x, wv4.x, oS0);
                oS1 = dot2(bA.x, wv4.y, oS1);
                ov0 = dot2(bA.z, wv4.z, dot2(bA.w, tv, ov0));
                ov1 = dot2(bB.x, wv4.z, dot2(bB.y, tv, ov1));
                ov2 = dot2(bB.z, wv4.z, dot2(bB.w, tv, ov2));
            } else {
                uint4 tw = ((const uint4*)tA)[cp*64 + lane];   // {tsa2, tsb2, tv2, pad}
                oS0 = dot2(bA.x, wv4.x, dot2(bA.y, tw.x, oS0));
                oS1 = dot2(bA.x, wv4.y, dot2(bA.y, tw.y, oS1));
                ov0 = dot2(bA.z, wv4.z, dot2(bA.w, tw.z, ov0));
                ov1 = dot2(bB.x, wv4.z, dot2(bB.y, tw.z, ov1));
                ov2 = dot2(bB.z, wv4.z, dot2(bB.w, tw.z, ov2));
                q2s = dot2(bA.y, wv4.w, q2s);
            }
            qv0 = dot2(bA.w, svr[cp], qv0);
            qv1 = dot2(bB.y, svr[cp], qv1);
            qv2 = dot2(bB.w, svr[cp], qv2);
        }
        float gs = silu_(oS0);
        float sg = sigm_(oS1);
        float gv0 = sg*ov0, gv1 = sg*ov1, gv2 = sg*ov2;
        float ns, nv0, nv1, nv2;
        if (L0) {
            ns  = hh*m*gs;
            nv0 = by0 + hh*(m*gv0 + (m-1.f)*qv0);
            nv1 = by1 + hh*(m*gv1 + (m-1.f)*qv1);
            nv2 = by2 + hh*(m*gv2 + (m-1.f)*qv2);
        } else {
            const float* yop = yoldv + (size_t)node*192 + lane*3;
            ns  = 2.f*ys_r + hh*(m*gs + (m-1.f)*q2s);
            nv0 = 2.f*by0 - yop[0] + hh*(m*gv0 + (m-1.f)*qv0);
            nv1 = 2.f*by1 - yop[1] + hh*(m*gv1 + (m-1.f)*qv1);
            nv2 = 2.f*by2 - yop[2] + hh*(m*gv2 + (m-1.f)*qv2);
        }
        if (L0) {
            newS[(size_t)node*64 + lane] = ns;
            float* np = newV + (size_t)node*192 + lane*3;
            np[0] = nv0; np[1] = nv1; np[2] = nv2;
        }
        float p00 = nv0*q0, p01 = nv1*q0, p02 = nv2*q0;
        float p10 = nv0*q1, p11 = nv1*q1, p12 = nv2*q1;
        for (int o = 32; o > 0; o >>= 1) {
            p00 += __shfl_xor(p00, o); p01 += __shfl_xor(p01, o); p02 += __shfl_xor(p02, o);
            p10 += __shfl_xor(p10, o); p11 += __shfl_xor(p11, o); p12 += __shfl_xor(p12, o);
        }
        if (lane == 0) {
            if (L0) {
                pos4out[node] = (float4){p00, p01, p02, 0.f};
            } else {
                float* xp = xout6 + (size_t)node*6;
                xp[0] = p00; xp[1] = p01; xp[2] = p02;
                xp[3] = p10; xp[4] = p11; xp[5] = p12;
            }
        }
    }
}

extern "C" void kernel_launch(void* const* d_in, const int* in_sizes, int n_in,
                              void* d_out, int out_size, void* d_ws, size_t ws_size,
                              hipStream_t stream) {
    const float* x        = (const float*)d_in[0];
    const int*   nattr    = (const int*)  d_in[2];
    const int*   esrc     = (const int*)  d_in[3];
    const int*   edst     = (const int*)  d_in[4];
    const float* embT     = (const float*)d_in[5];
    const float* upM      = (const float*)d_in[6];
    const float* hArr     = (const float*)d_in[7];
    const float* mArr     = (const float*)d_in[8];
    const float* rW1      = (const float*)d_in[9];
    const float* rb1      = (const float*)d_in[10];
    const float* rW2      = (const float*)d_in[11];
    const float* l1s      = (const float*)d_in[12];
    const float* l1v      = (const float*)d_in[13];
    const float* l2s      = (const float*)d_in[14];
    const float* l2v      = (const float*)d_in[15];
    const float* scs      = (const float*)d_in[16];
    const float* scv      = (const float*)d_in[17];
    const float* sis      = (const float*)d_in[18];
    const float* siv      = (const float*)d_in[19];
    int n = in_sizes[0] / 6;
    int e = in_sizes[3];
    float* out = (float*)d_out;

    // ---- workspace carve ----
    float* w = (float*)d_ws;
    float* Q    = w; w += 128;
    float* yAv  = w; w += (size_t)n*192;   // initial y_v (y_old_v for layer 1)
    float* yBs  = w; w += (size_t)n*64;
    float* yBv  = w; w += (size_t)n*192;
    float* aggS = w; w += (size_t)n*64;
    float* aggV = w; w += (size_t)n*192;
    float4* pos4 = (float4*)w; w += (size_t)n*4;
    uint2* mv    = (uint2*)w;  w += (size_t)n*128;           // n*64 uint2
    uint4* Tall  = (uint4*)w;  w += (size_t)2*NATTR*2048*4;  // 2*100*2048 uint4
    unsigned* radTab = (unsigned*)w; w += (size_t)2*(TBINS+1)*64;
    unsigned* siVp = (unsigned*)w; w += (size_t)2*2048;
    uint4* rec = (uint4*)w; w += (size_t)e*4;
    int* cnt   = (int*)w;
    int* offs  = cnt + n;
    int* curG0 = offs + (n + 1);
    int* curG1 = curG0 + n;
    size_t need = (size_t)((char*)(curG1 + n) - (char*)d_ws);
    if (need > ws_size) {
        fprintf(stderr, "kernel_launch: ws too small (%zu > %zu)\n", need, ws_size);
        return;
    }

    const int AGG_GRID  = 1792;  // 7 blocks/CU (20.7 KB LDS)
    const int OC_GRID   = 1024;  // 4 blocks/CU (36 KB LDS)
    const int LIN_GRID  = 2048;
    int eb = (e + 255)/256;

    kQ<<<1, 64, 0, stream>>>(upM, Q);
    hipMemsetAsync(cnt, 0, (size_t)n*sizeof(int), stream);
    kHist<<<eb, 256, 0, stream>>>(edst, cnt, e);
    kScan<<<1, 1024, 0, stream>>>(cnt, offs, curG0, curG1, n);
    kT3<<<dim3(32, 2, 5), 256, 0, stream>>>(embT, scs, scv, (unsigned*)Tall);
    kRadTab<<<dim3(TBINS+1, 2), 64, 0, stream>>>(rW1, rb1, rW2, radTab);
    kPackW<<<dim3(8, 2), 256, 0, stream>>>(siv, siVp);
    kInitLin<<<LIN_GRID, 256, 0, stream>>>(x, Q, l1v, yAv, pos4, mv, n);

    // ---- layer 0 (y_s == 0 analytically) ----
    kGeom<<<eb, 256, 0, stream>>>(pos4, esrc, edst, curG0, rec, e);
    kAgg<0><<<AGG_GRID, 256, 0, stream>>>(rec, mv, offs, curG0, radTab, aggS, aggV, n);
    kOutComb<1><<<OC_GRID, 256, 0, stream>>>(nullptr, yAv, nullptr, aggS, aggV, nattr,
                                  l2s, l2v, Tall, sis, siVp, Q, hArr, mArr, 0,
                                  yBs, yBv, pos4, out, n);
    // ---- layer 1 ----
    kLin1<<<LIN_GRID, 256, 0, stream>>>(yBs, yBv, l1s + 4096, l1v + 4096, mv, n);
    kGeom<<<eb, 256, 0, stream>>>(pos4, esrc, edst, curG1, rec, e);
    kAgg<1><<<AGG_GRID, 256, 0, stream>>>(rec, mv, offs, curG1,
                                  radTab + (size_t)(TBINS+1)*64, aggS, aggV, n);
    kOutComb<0><<<OC_GRID, 256, 0, stream>>>(yBs, yBv, yAv, aggS, aggV, nattr,
                                  l2s + (size_t)64*128, l2v + (size_t)64*64,
                                  Tall + (size_t)NATTR*2048,
                                  sis + 4096, siVp + 2048, Q, hArr, mArr, 1,
                                  nullptr, nullptr, nullptr, out, n);
}